// Round 4
// baseline (702.213 us; speedup 1.0000x reference)
//
#include <hip/hip_runtime.h>

#define N_NODES 100000
#define N_EDGES 400000
#define N_GRAPHS 4096
#define BN_EPS 1e-5f
#define DEG_CAP 96

typedef unsigned short ushort_t;
typedef short short8 __attribute__((ext_vector_type(8)));
typedef unsigned short ushort4v __attribute__((ext_vector_type(4)));
typedef unsigned short ushort8v __attribute__((ext_vector_type(8)));
typedef float floatx4 __attribute__((ext_vector_type(4)));

__device__ __forceinline__ ushort_t f2b(float f) {
    union { float f; unsigned u; } v; v.f = f;
    unsigned r = v.u + 0x7fffu + ((v.u >> 16) & 1u);
    return (ushort_t)(r >> 16);
}
__device__ __forceinline__ float b2f(ushort_t b) {
    union { unsigned u; float f; } v; v.u = ((unsigned)b) << 16;
    return v.f;
}

// ---------- prep0: zero cursor + prep BT1 = W1a^T (bf16, K-padded to 384) ----------
__global__ void k_prep0(int* __restrict__ cursor,
                        const float* __restrict__ W1a, ushort_t* __restrict__ BT1) {
    int t = threadIdx.x;   // 128
    int b = blockIdx.x;
    if (b < 782) {
        int i = b * 128 + t;
        if (i < N_NODES) cursor[i] = 0;
        return;
    }
    b -= 782;                            // 0..767
    int n = b / 3, kc = b % 3;
    int k = kc * 128 + t;
    float v = (k < 373) ? W1a[(long)k * 256 + n] : 0.f;
    BT1[(long)n * 384 + k] = f2b(v);
}

// ---------------- bucketed in-edge lists ----------------
__global__ void k_fill(const int* __restrict__ src, const int* __restrict__ dst,
                       int* __restrict__ cursor, int* __restrict__ elist) {
    int e = blockIdx.x * blockDim.x + threadIdx.x;
    if (e < N_EDGES) {
        int d = dst[e];
        int slot = atomicAdd(&cursor[d], 1);
        if (slot < DEG_CAP) elist[(long)d * DEG_CAP + slot] = src[e];
    }
}

// ---------- prep scaled: BT[n][k] = bf16(W[k][n]*sc[k]); biasE[n] = sum_k sh[k]W[k][n] ----------
__global__ void k_prep_scaled(const float* __restrict__ W, const float* __restrict__ scsh,
                              ushort_t* __restrict__ BT, float* __restrict__ biasE,
                              int K, int Kp, int Nn) {
    int n = blockIdx.y;
    int k = blockIdx.x * 128 + threadIdx.x;
    if (k < Kp) {
        float v = (k < K) ? W[(long)k * Nn + n] * scsh[k] : 0.f;
        BT[(long)n * Kp + k] = f2b(v);
    }
    if (blockIdx.x == 0) {
        __shared__ float red[2];
        float s = 0.f;
        for (int kk = threadIdx.x; kk < K; kk += 128) s += scsh[K + kk] * W[(long)kk * Nn + n];
#pragma unroll
        for (int off = 32; off >= 1; off >>= 1) s += __shfl_xor(s, off);
        if ((threadIdx.x & 63) == 0) red[threadIdx.x >> 6] = s;
        __syncthreads();
        if (threadIdx.x == 0) biasE[n] = red[0] + red[1];
    }
}

// ---------------- fused pad/convert + layer-1a GEMM: C = bf16(x) @ W1a^T ----------------
// 128 rows x 256 cols per block, gx=1 (x read exactly once). A reg-staged from f32
// (16 scalar loads/thread/K-step -> bf16 -> ds_write_b128, stride-40 rows), B via
// global_load_lds. 2x2 waves, each 64r x 128c (acc[4][8]). No bias/relu (layer-1a).
__global__ __launch_bounds__(256) void k_gemm_x(const float* __restrict__ x,
                                                const ushort_t* __restrict__ BT,
                                                ushort_t* __restrict__ C, int M) {
    __shared__ __align__(16) ushort_t As[128 * 40];   // stride 40: read 2-way max
    __shared__ __align__(16) ushort_t Bs[256 * 32];
    const int tid = threadIdx.x;
    const int wave = tid >> 6, lane = tid & 63;
    const int ln = lane & 15, kg = lane >> 4;
    const long rowBase = (long)blockIdx.x * 128;
    const int rowOff = (wave >> 1) * 64;
    const int colOff = (wave & 1) * 128;

    // staging map: row = tid>>1, 16 cols starting at (tid&1)*16
    const int sr = tid >> 1;
    const int sc0 = (tid & 1) * 16;
    long gr = rowBase + sr; if (gr >= M) gr = M - 1;
    const float* xr = x + gr * 373;

    const ushort_t* bSrc[4];
#pragma unroll
    for (int i = 0; i < 4; i++) {
        long cc = i * 64 + (tid >> 2);
        bSrc[i] = BT + cc * 384 + (tid & 3) * 8;
    }
    ushort_t* bDst = Bs + wave * 512;

    floatx4 acc[4][8];
#pragma unroll
    for (int i = 0; i < 4; i++)
#pragma unroll
        for (int j = 0; j < 8; j++) acc[i][j] = (floatx4){0.f, 0.f, 0.f, 0.f};

    for (int k0 = 0; k0 < 384; k0 += 32) {
        __syncthreads();
        // stage A: f32 -> bf16
        ushort8v o0, o1;
#pragma unroll
        for (int j = 0; j < 8; j++) {
            int c = k0 + sc0 + j;
            o0[j] = f2b((c < 373) ? xr[c] : 0.f);
        }
#pragma unroll
        for (int j = 0; j < 8; j++) {
            int c = k0 + sc0 + 8 + j;
            o1[j] = f2b((c < 373) ? xr[c] : 0.f);
        }
        *(ushort8v*)&As[sr * 40 + sc0] = o0;
        *(ushort8v*)&As[sr * 40 + sc0 + 8] = o1;
        // stage B
#pragma unroll
        for (int i = 0; i < 4; i++)
            __builtin_amdgcn_global_load_lds(
                (const __attribute__((address_space(1))) void*)(bSrc[i] + k0),
                (__attribute__((address_space(3))) void*)(bDst + i * 2048), 16, 0, 0);
        __syncthreads();

        short8 afr[4], bfr[8];
#pragma unroll
        for (int rt = 0; rt < 4; rt++)
            afr[rt] = *(const short8*)&As[(rowOff + rt * 16 + ln) * 40 + kg * 8];
#pragma unroll
        for (int ct = 0; ct < 8; ct++)
            bfr[ct] = *(const short8*)&Bs[(colOff + ct * 16 + ln) * 32 + kg * 8];
#pragma unroll
        for (int rt = 0; rt < 4; rt++)
#pragma unroll
            for (int ct = 0; ct < 8; ct++)
                acc[rt][ct] = __builtin_amdgcn_mfma_f32_16x16x32_bf16(afr[rt], bfr[ct], acc[rt][ct], 0, 0, 0);
    }

#pragma unroll
    for (int rt = 0; rt < 4; rt++) {
#pragma unroll
        for (int ct = 0; ct < 8; ct++) {
            int gc = colOff + ct * 16 + ln;
#pragma unroll
            for (int r = 0; r < 4; r++) {
                long g2 = rowBase + rowOff + rt * 16 + kg * 4 + r;
                if (g2 < M) C[g2 * 256 + gc] = f2b(acc[rt][ct][r]);
            }
        }
    }
}

// ---------------- MFMA GEMM, optional fused BN-stats partials ----------------
// TN=64: 4x1 waves 32rx64c; TN=128: 2x2 waves 64rx64c; TN=256: 2x2 waves 64rx128c.
template<int KP, int TN, bool STATS>
__global__ __launch_bounds__(256) void k_gemm(const ushort_t* __restrict__ A,
                                              const ushort_t* __restrict__ BT,
                                              const float* __restrict__ bias,
                                              ushort_t* __restrict__ C,
                                              float* __restrict__ partials,
                                              int M, int Nn, int relu) {
    __shared__ __align__(16) ushort_t As[128 * 32];
    __shared__ __align__(16) ushort_t Bs[TN * 32];
    __shared__ float swred[STATS ? 4 * 2 * TN : 1];
    const int tid = threadIdx.x;
    const int wave = tid >> 6, lane = tid & 63;
    const int ln = lane & 15, kg = lane >> 4;
    const long rowBase = (long)blockIdx.y * 128;
    const int colBase = blockIdx.x * TN;

    constexpr int RT = (TN == 64) ? 2 : 4;
    constexpr int CT = (TN == 256) ? 8 : 4;
    const int rowOff = (TN == 64) ? (wave * 32) : ((wave >> 1) * 64);
    const int colOff = (TN == 64) ? 0 : ((wave & 1) * (CT * 16));

    const ushort_t* aSrc[2];
#pragma unroll
    for (int i = 0; i < 2; i++) {
        long r = rowBase + i * 64 + (tid >> 2);
        if (r >= M) r = M - 1;
        aSrc[i] = A + r * KP + (tid & 3) * 8;
    }
    const ushort_t* bSrc[TN / 64];
#pragma unroll
    for (int i = 0; i < TN / 64; i++) {
        long cc = colBase + i * 64 + (tid >> 2);
        bSrc[i] = BT + cc * KP + (tid & 3) * 8;
    }
    ushort_t* aDst = As + wave * 512;
    ushort_t* bDst = Bs + wave * 512;

    floatx4 acc[RT][CT];
#pragma unroll
    for (int i = 0; i < RT; i++)
#pragma unroll
        for (int j = 0; j < CT; j++) acc[i][j] = (floatx4){0.f, 0.f, 0.f, 0.f};

    for (int k0 = 0; k0 < KP; k0 += 32) {
        __syncthreads();
#pragma unroll
        for (int i = 0; i < 2; i++)
            __builtin_amdgcn_global_load_lds(
                (const __attribute__((address_space(1))) void*)(aSrc[i] + k0),
                (__attribute__((address_space(3))) void*)(aDst + i * 2048), 16, 0, 0);
#pragma unroll
        for (int i = 0; i < TN / 64; i++)
            __builtin_amdgcn_global_load_lds(
                (const __attribute__((address_space(1))) void*)(bSrc[i] + k0),
                (__attribute__((address_space(3))) void*)(bDst + i * 2048), 16, 0, 0);
        __syncthreads();

        short8 afr[RT], bfr[CT];
#pragma unroll
        for (int rt = 0; rt < RT; rt++)
            afr[rt] = *(const short8*)&As[(rowOff + rt * 16 + ln) * 32 + kg * 8];
#pragma unroll
        for (int tn = 0; tn < CT; tn++)
            bfr[tn] = *(const short8*)&Bs[(colOff + tn * 16 + ln) * 32 + kg * 8];
#pragma unroll
        for (int rt = 0; rt < RT; rt++)
#pragma unroll
            for (int tn = 0; tn < CT; tn++)
                acc[rt][tn] = __builtin_amdgcn_mfma_f32_16x16x32_bf16(afr[rt], bfr[tn], acc[rt][tn], 0, 0, 0);
    }

    if constexpr (STATS) {
        for (int i = tid; i < 4 * 2 * TN; i += 256) swred[i] = 0.f;
        __syncthreads();
    }

    float sums[CT], sqs[CT];
#pragma unroll
    for (int tn = 0; tn < CT; tn++) { sums[tn] = 0.f; sqs[tn] = 0.f; }
#pragma unroll
    for (int rt = 0; rt < RT; rt++) {
#pragma unroll
        for (int tn = 0; tn < CT; tn++) {
            int gc = colBase + colOff + tn * 16 + ln;
            float bv = bias ? bias[gc] : 0.f;
#pragma unroll
            for (int r = 0; r < 4; r++) {
                long gr = rowBase + rowOff + rt * 16 + kg * 4 + r;
                if (gr < M) {
                    float v = acc[rt][tn][r] + bv;
                    if (relu) v = fmaxf(v, 0.f);
                    ushort_t sb = f2b(v);
                    C[gr * Nn + gc] = sb;
                    if (STATS) {
                        float vb = b2f(sb);
                        sums[tn] += vb;
                        sqs[tn] += vb * vb;
                    }
                }
            }
        }
    }
    if constexpr (STATS) {
#pragma unroll
        for (int tn = 0; tn < CT; tn++) {
            float s = sums[tn], q = sqs[tn];
            s += __shfl_xor(s, 16); q += __shfl_xor(q, 16);
            s += __shfl_xor(s, 32); q += __shfl_xor(q, 32);
            if (kg == 0) {
                int c = colOff + tn * 16 + ln;
                swred[wave * 2 * TN + c] = s;
                swred[wave * 2 * TN + TN + c] = q;
            }
        }
        __syncthreads();
        const int by = blockIdx.y;
        const int gyd = gridDim.y;
        for (int c = tid; c < TN; c += 256) {
            float ssum = 0.f, ssq = 0.f;
#pragma unroll
            for (int w = 0; w < 4; w++) {
                ssum += swred[w * 2 * TN + c];
                ssq  += swred[w * 2 * TN + TN + c];
            }
            long gc = colBase + c;
            partials[gc * gyd + by] = ssum;
            partials[((long)Nn + gc) * gyd + by] = ssq;
        }
    }
}

// ---------------- fused aggregate + MFMA GEMM (gx=1 layers) ----------------
template<int KP, int TN>
__global__ __launch_bounds__(256, 4) void k_gemm_agg(const ushort_t* __restrict__ y,
                                                  const int* __restrict__ cursor,
                                                  const int* __restrict__ elist,
                                                  const float* __restrict__ badd,
                                                  const ushort_t* __restrict__ BT,
                                                  const float* __restrict__ bias,
                                                  ushort_t* __restrict__ C,
                                                  float* __restrict__ partials,
                                                  int M, int Nn) {
    __shared__ __align__(16) ushort_t Af[128 * KP];
    __shared__ __align__(16) ushort_t Bs[TN * 32];
    float* swred = (float*)Af;           // alias: Af dead after K-loop (barrier below)
    const int tid = threadIdx.x;
    const int wave = tid >> 6, lane = tid & 63;
    const int ln = lane & 15, kg = lane >> 4;
    const long rowBase = (long)blockIdx.y * 128;
    constexpr int CPR = KP / 8;          // 16B chunks per row
    constexpr int TPR = CPR;
    constexpr int RPS = 256 / TPR;

    // ---- phase 1: aggregate into Af (chunk-XOR swizzle keyed on row) ----
    {
        const int lr = tid / TPR;
        const int ck = tid % TPR;
        const int c0 = ck * 8;
        float bd[8];
#pragma unroll
        for (int j = 0; j < 8; j++) bd[j] = badd[c0 + j];
        for (int s = 0; s < 128; s += RPS) {
            int r = s + lr;
            long gr = rowBase + r; if (gr >= M) gr = M - 1;
            int cnt = cursor[gr]; if (cnt > DEG_CAP) cnt = DEG_CAP;
            const int* el = elist + gr * DEG_CAP;
            int4 e0 = *(const int4*)el;
            int4 e1 = *(const int4*)(el + 4);
            int ids[8] = {e0.x, e0.y, e0.z, e0.w, e1.x, e1.y, e1.z, e1.w};
            ushort8v sv = *(const ushort8v*)(y + gr * KP + c0);
            ushort8v rr[8];
#pragma unroll
            for (int i = 0; i < 8; i++)
                if (i < cnt) rr[i] = *(const ushort8v*)(y + (long)ids[i] * KP + c0);
            float av[8];
#pragma unroll
            for (int j = 0; j < 8; j++) av[j] = b2f(sv[j]);
#pragma unroll
            for (int i = 0; i < 8; i++)
                if (i < cnt) {
#pragma unroll
                    for (int j = 0; j < 8; j++) av[j] += b2f(rr[i][j]);
                }
            for (int i = 8; i < cnt; i++) {
                ushort8v u = *(const ushort8v*)(y + (long)el[i] * KP + c0);
#pragma unroll
                for (int j = 0; j < 8; j++) av[j] += b2f(u[j]);
            }
            ushort8v ov;
#pragma unroll
            for (int j = 0; j < 8; j++) ov[j] = f2b(fmaxf(av[j] + bd[j], 0.f));
            int cks = ck ^ (r & (CPR - 1));
            *(ushort8v*)&Af[r * KP + cks * 8] = ov;
        }
    }

    // ---- phase 2: GEMM, A from LDS, B staged ----
    constexpr int RT = (TN == 128) ? 4 : 2;
    const int rowOff = (TN == 128) ? ((wave >> 1) * 64) : (wave * 32);
    const int colOff = (TN == 128) ? ((wave & 1) * 64) : 0;
    const ushort_t* bSrc[TN / 64];
#pragma unroll
    for (int i = 0; i < TN / 64; i++) {
        long cc = i * 64 + (tid >> 2);
        bSrc[i] = BT + cc * KP + (tid & 3) * 8;
    }
    ushort_t* bDst = Bs + wave * 512;

    floatx4 acc[RT][4];
#pragma unroll
    for (int i = 0; i < RT; i++)
#pragma unroll
        for (int j = 0; j < 4; j++) acc[i][j] = (floatx4){0.f, 0.f, 0.f, 0.f};

    for (int k0 = 0; k0 < KP; k0 += 32) {
        __syncthreads();
#pragma unroll
        for (int i = 0; i < TN / 64; i++)
            __builtin_amdgcn_global_load_lds(
                (const __attribute__((address_space(1))) void*)(bSrc[i] + k0),
                (__attribute__((address_space(3))) void*)(bDst + i * 2048), 16, 0, 0);
        __syncthreads();

        short8 afr[RT], bfr[4];
#pragma unroll
        for (int rt = 0; rt < RT; rt++) {
            int row = rowOff + rt * 16 + ln;
            int cks = ((k0 >> 3) + kg) ^ (row & (CPR - 1));
            afr[rt] = *(const short8*)&Af[row * KP + cks * 8];
        }
#pragma unroll
        for (int tn = 0; tn < 4; tn++)
            bfr[tn] = *(const short8*)&Bs[(colOff + tn * 16 + ln) * 32 + kg * 8];
#pragma unroll
        for (int rt = 0; rt < RT; rt++)
#pragma unroll
            for (int tn = 0; tn < 4; tn++)
                acc[rt][tn] = __builtin_amdgcn_mfma_f32_16x16x32_bf16(afr[rt], bfr[tn], acc[rt][tn], 0, 0, 0);
    }

    __syncthreads();
    for (int i = tid; i < 4 * 2 * TN; i += 256) swred[i] = 0.f;
    __syncthreads();

    float sums[4] = {0.f, 0.f, 0.f, 0.f};
    float sqs[4]  = {0.f, 0.f, 0.f, 0.f};
#pragma unroll
    for (int rt = 0; rt < RT; rt++) {
#pragma unroll
        for (int tn = 0; tn < 4; tn++) {
            int gc = colOff + tn * 16 + ln;
            float bv = bias[gc];
#pragma unroll
            for (int r = 0; r < 4; r++) {
                long gr = rowBase + rowOff + rt * 16 + kg * 4 + r;
                if (gr < M) {
                    float v = fmaxf(acc[rt][tn][r] + bv, 0.f);
                    ushort_t sb = f2b(v);
                    C[gr * Nn + gc] = sb;
                    float vb = b2f(sb);
                    sums[tn] += vb;
                    sqs[tn] += vb * vb;
                }
            }
        }
    }
#pragma unroll
    for (int tn = 0; tn < 4; tn++) {
        float s = sums[tn], q = sqs[tn];
        s += __shfl_xor(s, 16); q += __shfl_xor(q, 16);
        s += __shfl_xor(s, 32); q += __shfl_xor(q, 32);
        if (kg == 0) {
            int c = colOff + tn * 16 + ln;
            swred[wave * 2 * TN + c] = s;
            swred[wave * 2 * TN + TN + c] = q;
        }
    }
    __syncthreads();
    const int by = blockIdx.y;
    const int gyd = gridDim.y;
    for (int c = tid; c < TN; c += 256) {
        float ssum = 0.f, ssq = 0.f;
#pragma unroll
        for (int w = 0; w < 4; w++) {
            ssum += swred[w * 2 * TN + c];
            ssq  += swred[w * 2 * TN + TN + c];
        }
        partials[(long)c * gyd + by] = ssum;
        partials[((long)Nn + c) * gyd + by] = ssq;
    }
}

// ---------- standalone aggregate (layer 1, D=256), depth-8 MLP + fused W1b prep ----------
template<int D>
__global__ void k_aggregate(const ushort_t* __restrict__ y, const int* __restrict__ cursor,
                            const int* __restrict__ elist, const float* __restrict__ badd,
                            ushort_t* __restrict__ out, int nblk,
                            const float* __restrict__ Wn, ushort_t* __restrict__ BTn,
                            int KWn, int NWn) {
    int t = threadIdx.x;
    if ((int)blockIdx.x >= nblk) {
        int b = blockIdx.x - nblk;
        int nk = KWn >> 6;
        int n = b / nk, kc = b - n * nk;
        int k = kc * 64 + t;
        BTn[(long)n * KWn + k] = f2b(Wn[(long)k * NWn + n]);
        return;
    }
    const int CG = D / 4;
    const int NPB = 64 / CG;
    int n = blockIdx.x * NPB + t / CG;
    int c = (t % CG) * 4;
    if (n >= N_NODES) return;
    int cnt = cursor[n];
    if (cnt > DEG_CAP) cnt = DEG_CAP;
    const int* el = elist + (long)n * DEG_CAP;
    int4 e0 = *(const int4*)el;
    int4 e1 = *(const int4*)(el + 4);
    int ids[8] = {e0.x, e0.y, e0.z, e0.w, e1.x, e1.y, e1.z, e1.w};
    ushort4v sv = *(const ushort4v*)(y + (long)n * D + c);
    ushort4v rr[8];
#pragma unroll
    for (int i = 0; i < 8; i++)
        if (i < cnt) rr[i] = *(const ushort4v*)(y + (long)ids[i] * D + c);
    float t0 = b2f(sv.x), t1 = b2f(sv.y), t2 = b2f(sv.z), t3 = b2f(sv.w);
#pragma unroll
    for (int i = 0; i < 8; i++)
        if (i < cnt) {
            t0 += b2f(rr[i].x); t1 += b2f(rr[i].y); t2 += b2f(rr[i].z); t3 += b2f(rr[i].w);
        }
    for (int i = 8; i < cnt; i++) {
        ushort4v u = *(const ushort4v*)(y + (long)el[i] * D + c);
        t0 += b2f(u.x); t1 += b2f(u.y); t2 += b2f(u.z); t3 += b2f(u.w);
    }
    t0 = fmaxf(t0 + badd[c + 0], 0.f);
    t1 = fmaxf(t1 + badd[c + 1], 0.f);
    t2 = fmaxf(t2 + badd[c + 2], 0.f);
    t3 = fmaxf(t3 + badd[c + 3], 0.f);
    ushort4v o = {f2b(t0), f2b(t1), f2b(t2), f2b(t3)};
    *(ushort4v*)(out + (long)n * D + c) = o;
}

// ---------- BN: reduce partials + finalize scsh; optional next-W prep ----------
__global__ void k_bn(const float* __restrict__ partials, int gy,
                     const float* __restrict__ gamma, const float* __restrict__ beta,
                     float* __restrict__ scsh, int K,
                     const float* __restrict__ Wn, ushort_t* __restrict__ BTn,
                     int KWn, int NWn) {
    int b = blockIdx.x;
    int t = threadIdx.x;   // 64
    if (b >= K) {
        int p = b - K;
        int nk = KWn >> 6;
        int n = p / nk, kc = p - n * nk;
        int k = kc * 64 + t;
        BTn[(long)n * KWn + k] = f2b(Wn[(long)k * NWn + n]);
        return;
    }
    const float* ps = partials + (long)b * gy;
    const float* pq = partials + (long)(K + b) * gy;
    float s = 0.f, q = 0.f;
    for (int i = t; i < gy; i += 64) { s += ps[i]; q += pq[i]; }
#pragma unroll
    for (int off = 32; off >= 1; off >>= 1) { s += __shfl_xor(s, off); q += __shfl_xor(q, off); }
    if (t == 0) {
        float invN = 1.0f / (float)N_NODES;
        float mu = s * invN;
        float var = fmaxf(q * invN - mu * mu, 0.f);
        float sc = rsqrtf(var + BN_EPS) * gamma[b];
        scsh[b] = sc;
        scsh[K + b] = beta[b] - mu * sc;
    }
}

// ---------- pool (segmented, BN affine fused) + head, fused ----------
__global__ void k_poolhead(const ushort_t* __restrict__ h, const int* __restrict__ batch,
                           const float* __restrict__ scsh,
                           const float* __restrict__ Wf1, const float* __restrict__ bf1,
                           const float* __restrict__ Wf2, const float* __restrict__ bf2,
                           float* __restrict__ out) {
    __shared__ float pl[64];
    __shared__ float hid[16];
    int g = blockIdx.x;
    int c = threadIdx.x;
    int lo = 0, hi = N_NODES;
    while (lo < hi) { int mid = (lo + hi) >> 1; if (batch[mid] < g) lo = mid + 1; else hi = mid; }
    int start = lo;
    hi = N_NODES;
    while (lo < hi) { int mid = (lo + hi) >> 1; if (batch[mid] < g + 1) lo = mid + 1; else hi = mid; }
    int end = lo;
    float s = 0.f;
    for (int r = start; r < end; r++) s += b2f(h[(long)r * 64 + c]);
    pl[c] = s * scsh[c] + scsh[64 + c] * (float)(end - start);
    __syncthreads();
    if (c < 16) {
        float sh = bf1[c];
        for (int j = 0; j < 64; j++) sh += pl[j] * Wf1[j * 16 + c];
        hid[c] = fmaxf(sh, 0.f);
    }
    __syncthreads();
    if (c == 0) {
        float o = bf2[0];
#pragma unroll
        for (int k = 0; k < 16; k++) o += hid[k] * Wf2[k];
        out[g] = fmaxf(o, 0.f);
    }
}

// ---------------- launch ----------------
extern "C" void kernel_launch(void* const* d_in, const int* in_sizes, int n_in,
                              void* d_out, int out_size, void* d_ws, size_t ws_size,
                              hipStream_t stream) {
    const float* x    = (const float*)d_in[0];
    const int*  ei    = (const int*)d_in[1];
    const int*  batch = (const int*)d_in[2];
    const float* W1a = (const float*)d_in[3];
    const float* b1a = (const float*)d_in[4];
    const float* W1b = (const float*)d_in[5];
    const float* b1b = (const float*)d_in[6];
    const float* g1  = (const float*)d_in[7];
    const float* be1 = (const float*)d_in[8];
    const float* W2a = (const float*)d_in[9];
    const float* b2a = (const float*)d_in[10];
    const float* W2b = (const float*)d_in[11];
    const float* b2b = (const float*)d_in[12];
    const float* g2  = (const float*)d_in[13];
    const float* be2 = (const float*)d_in[14];
    const float* W3a = (const float*)d_in[15];
    const float* b3a = (const float*)d_in[16];
    const float* W3b = (const float*)d_in[17];
    const float* b3b = (const float*)d_in[18];
    const float* g3  = (const float*)d_in[19];
    const float* be3 = (const float*)d_in[20];
    const float* Wf1 = (const float*)d_in[21];
    const float* bf1 = (const float*)d_in[22];
    const float* Wf2 = (const float*)d_in[23];
    const float* bf2 = (const float*)d_in[24];

    const int N = N_NODES, E = N_EDGES;
    const int* src = ei;
    const int* dst = ei + E;
    const int gy = (N + 127) / 128;   // 782 row-tiles

    // ---- workspace carve (256B aligned) ----
    char* wp = (char*)d_ws;
    auto carve = [&](size_t bytes) {
        char* p = wp;
        wp += (bytes + 255) & ~(size_t)255;
        return (void*)p;
    };
    ushort_t* bufA   = (ushort_t*)carve((size_t)N * 256 * 2);
    ushort_t* bufB   = (ushort_t*)carve((size_t)N * 256 * 2);
    int*      elist  = (int*)carve((size_t)N * DEG_CAP * 4);
    int*      cursor = (int*)carve((size_t)N * 4);
    ushort_t* BT1    = (ushort_t*)carve((size_t)256 * 384 * 2);
    ushort_t* BT2    = (ushort_t*)carve((size_t)256 * 384 * 2);
    float*    scsh   = (float*)carve(512 * 4);
    float*    biasE  = (float*)carve(256 * 4);
    float*    partials = (float*)carve((size_t)2 * 256 * gy * 4);  // 1.6 MB max

    dim3 blk(256);

    // ---- prep: zero cursor + W1a prep; build in-edge buckets ----
    k_prep0<<<782 + 768, 128, 0, stream>>>(cursor, W1a, BT1);
    k_fill<<<(E + 255) / 256, blk, 0, stream>>>(src, dst, cursor, elist);

    // ---------- layer 1: 373 -> 256 -> 256 ----------
    k_gemm_x<<<gy, blk, 0, stream>>>(x, BT1, bufA, N);                 // fused pad+GEMM, x read once
    k_aggregate<256><<<N + 1024, 64, 0, stream>>>(bufA, cursor, elist, b1a, bufB, N, W1b, BT2, 256, 256);
    k_gemm<256, 256, true><<<dim3(1, gy), blk, 0, stream>>>(bufB, BT2, b1b, bufA, partials, N, 256, 1);
    k_bn<<<256 + 256, 64, 0, stream>>>(partials, gy, g1, be1, scsh, 256, W2b, BT2, 128, 128);

    // ---------- layer 2: 256 -> 128 -> 128 (BN folded into W2a + biasEff) ----------
    k_prep_scaled<<<dim3(2, 128), 128, 0, stream>>>(W2a, scsh, BT1, biasE, 256, 256, 128);
    k_gemm<256, 128, false><<<dim3(1, gy), blk, 0, stream>>>(bufA, BT1, biasE, bufB, nullptr, N, 128, 0);
    k_gemm_agg<128, 128><<<dim3(1, gy), blk, 0, stream>>>(bufB, cursor, elist, b2a, BT2, b2b, bufA, partials, N, 128);
    k_bn<<<128 + 64, 64, 0, stream>>>(partials, gy, g2, be2, scsh, 128, W3b, BT2, 64, 64);

    // ---------- layer 3: 128 -> 64 -> 64 ----------
    k_prep_scaled<<<dim3(1, 64), 128, 0, stream>>>(W3a, scsh, BT1, biasE, 128, 128, 64);
    k_gemm<128, 64, false><<<dim3(1, gy), blk, 0, stream>>>(bufA, BT1, biasE, bufB, nullptr, N, 64, 0);
    k_gemm_agg<64, 64><<<dim3(1, gy), blk, 0, stream>>>(bufB, cursor, elist, b3a, BT2, b3b, bufA, partials, N, 64);
    k_bn<<<64, 64, 0, stream>>>(partials, gy, g3, be3, scsh, 64, nullptr, nullptr, 64, 64);

    // ---------- pool + head (fused) ----------
    k_poolhead<<<N_GRAPHS, 64, 0, stream>>>(bufA, batch, scsh, Wf1, bf1, Wf2, bf2, (float*)d_out);
}

// Round 5
// 614.331 us; speedup vs baseline: 1.1431x; 1.1431x over previous
//
#include <hip/hip_runtime.h>

#define N_NODES 100000
#define N_EDGES 400000
#define N_GRAPHS 4096
#define BN_EPS 1e-5f
#define DEG_CAP 32

typedef unsigned short ushort_t;
typedef short short8 __attribute__((ext_vector_type(8)));
typedef unsigned short ushort4v __attribute__((ext_vector_type(4)));
typedef unsigned short ushort8v __attribute__((ext_vector_type(8)));
typedef float floatx4 __attribute__((ext_vector_type(4)));

__device__ __forceinline__ ushort_t f2b(float f) {
    union { float f; unsigned u; } v; v.f = f;
    unsigned r = v.u + 0x7fffu + ((v.u >> 16) & 1u);
    return (ushort_t)(r >> 16);
}
__device__ __forceinline__ float b2f(ushort_t b) {
    union { unsigned u; float f; } v; v.u = ((unsigned)b) << 16;
    return v.f;
}

// ---------- pad + convert x -> bf16 [N][384]; zero cursor; prep BT1=W1a^T ----------
__global__ void k_pad_x(const float* __restrict__ x, ushort_t* __restrict__ xb,
                        int* __restrict__ cursor,
                        const float* __restrict__ W1a, ushort_t* __restrict__ BT1) {
    int t = threadIdx.x;   // 128
    if (blockIdx.x >= N_NODES) {
        int b = blockIdx.x - N_NODES;        // 0..767 : prep W1a -> BT1 [256][384]
        int n = b / 3, kc = b % 3;
        int k = kc * 128 + t;
        float v = (k < 373) ? W1a[(long)k * 256 + n] : 0.f;
        BT1[(long)n * 384 + k] = f2b(v);
        return;
    }
    int n = blockIdx.x;
    const float* xr = x + (long)n * 373;
    ushort_t* o = xb + (long)n * 384;
    if (t < 93) {
        float v0 = xr[t * 4 + 0], v1 = xr[t * 4 + 1], v2 = xr[t * 4 + 2], v3 = xr[t * 4 + 3];
        ushort4v s = {f2b(v0), f2b(v1), f2b(v2), f2b(v3)};
        *(ushort4v*)(o + t * 4) = s;
    } else if (t == 93) {
        o[372] = f2b(xr[372]);
        o[373] = 0; o[374] = 0; o[375] = 0;
    } else if (t == 94 || t == 95) {
        ushort4v z = {0, 0, 0, 0};
        *(ushort4v*)(o + 376 + (t - 94) * 4) = z;
    } else if (t == 96) {
        cursor[n] = 0;
    }
}

// ---------------- bucketed in-edge lists ----------------
__global__ void k_fill(const int* __restrict__ src, const int* __restrict__ dst,
                       int* __restrict__ cursor, int* __restrict__ elist) {
    int e = blockIdx.x * blockDim.x + threadIdx.x;
    if (e < N_EDGES) {
        int d = dst[e];
        int slot = atomicAdd(&cursor[d], 1);
        if (slot < DEG_CAP) elist[(long)d * DEG_CAP + slot] = src[e];
    }
}

// ---------- prep scaled: BT[n][k] = bf16(W[k][n]*sc[k]); biasE[n] = sum_k sh[k]W[k][n] ----------
__global__ void k_prep_scaled(const float* __restrict__ W, const float* __restrict__ scsh,
                              ushort_t* __restrict__ BT, float* __restrict__ biasE,
                              int K, int Kp, int Nn) {
    int n = blockIdx.y;
    int k = blockIdx.x * 128 + threadIdx.x;
    if (k < Kp) {
        float v = (k < K) ? W[(long)k * Nn + n] * scsh[k] : 0.f;
        BT[(long)n * Kp + k] = f2b(v);
    }
    if (blockIdx.x == 0) {
        __shared__ float red[2];
        float s = 0.f;
        for (int kk = threadIdx.x; kk < K; kk += 128) s += scsh[K + kk] * W[(long)kk * Nn + n];
#pragma unroll
        for (int off = 32; off >= 1; off >>= 1) s += __shfl_xor(s, off);
        if ((threadIdx.x & 63) == 0) red[threadIdx.x >> 6] = s;
        __syncthreads();
        if (threadIdx.x == 0) biasE[n] = red[0] + red[1];
    }
}

// ---------------- MFMA GEMM, 2-phase double-buffered, optional fused BN-stats ----------------
// One barrier per K-step: stage(next tile) issued BEFORE compute(current), so the
// vmcnt(0) drain at the next __syncthreads lands after a full MFMA phase of overlap.
// Grid (>=782 blocks) limits residency to ~3-6 blocks/CU, so the 2x LDS is free.
template<int KP, int TN, bool STATS>
__global__ __launch_bounds__(256) void k_gemm(const ushort_t* __restrict__ A,
                                              const ushort_t* __restrict__ BT,
                                              const float* __restrict__ bias,
                                              ushort_t* __restrict__ C,
                                              float* __restrict__ partials,
                                              int M, int Nn, int relu) {
    __shared__ __align__(16) ushort_t As[2][128 * 32];
    __shared__ __align__(16) ushort_t Bs[2][TN * 32];
    float* swred = (float*)As;    // STATS scratch aliases As (barrier-separated)
    const int tid = threadIdx.x;
    const int wave = tid >> 6, lane = tid & 63;
    const int ln = lane & 15, kg = lane >> 4;
    const long rowBase = (long)blockIdx.y * 128;
    const int colBase = blockIdx.x * TN;

    constexpr int RT = (TN == 128) ? 4 : 2;
    const int rowOff = (TN == 128) ? ((wave >> 1) * 64) : (wave * 32);
    const int colOff = (TN == 128) ? ((wave & 1) * 64) : 0;

    const ushort_t* aSrc[2];
#pragma unroll
    for (int i = 0; i < 2; i++) {
        long r = rowBase + i * 64 + (tid >> 2);
        if (r >= M) r = M - 1;
        aSrc[i] = A + r * KP + (tid & 3) * 8;
    }
    const ushort_t* bSrc[TN / 64];
#pragma unroll
    for (int i = 0; i < TN / 64; i++) {
        long cc = colBase + i * 64 + (tid >> 2);
        bSrc[i] = BT + cc * KP + (tid & 3) * 8;
    }

    auto stage = [&](int b, int k0) {
#pragma unroll
        for (int i = 0; i < 2; i++)
            __builtin_amdgcn_global_load_lds(
                (const __attribute__((address_space(1))) void*)(aSrc[i] + k0),
                (__attribute__((address_space(3))) void*)(As[b] + wave * 512 + i * 2048), 16, 0, 0);
#pragma unroll
        for (int i = 0; i < TN / 64; i++)
            __builtin_amdgcn_global_load_lds(
                (const __attribute__((address_space(1))) void*)(bSrc[i] + k0),
                (__attribute__((address_space(3))) void*)(Bs[b] + wave * 512 + i * 2048), 16, 0, 0);
    };

    floatx4 acc[RT][4];
#pragma unroll
    for (int i = 0; i < RT; i++)
#pragma unroll
        for (int j = 0; j < 4; j++) acc[i][j] = (floatx4){0.f, 0.f, 0.f, 0.f};

    stage(0, 0);                     // prologue
    int cur = 0;
    for (int k0 = 0; k0 < KP; k0 += 32) {
        __syncthreads();             // drains stage(cur) loads; ends reads of buf cur^1
        if (k0 + 32 < KP) stage(cur ^ 1, k0 + 32);   // overlap with MFMA below

        short8 afr[RT], bfr[4];
#pragma unroll
        for (int rt = 0; rt < RT; rt++)
            afr[rt] = *(const short8*)&As[cur][(rowOff + rt * 16 + ln) * 32 + kg * 8];
#pragma unroll
        for (int tn = 0; tn < 4; tn++)
            bfr[tn] = *(const short8*)&Bs[cur][(colOff + tn * 16 + ln) * 32 + kg * 8];
#pragma unroll
        for (int rt = 0; rt < RT; rt++)
#pragma unroll
            for (int tn = 0; tn < 4; tn++)
                acc[rt][tn] = __builtin_amdgcn_mfma_f32_16x16x32_bf16(afr[rt], bfr[tn], acc[rt][tn], 0, 0, 0);
        cur ^= 1;
    }

    if constexpr (STATS) {
        __syncthreads();             // all ds_reads of As done before aliasing as swred
        for (int i = tid; i < 4 * 2 * TN; i += 256) swred[i] = 0.f;
        __syncthreads();
    }

    float sums[4] = {0.f, 0.f, 0.f, 0.f};
    float sqs[4]  = {0.f, 0.f, 0.f, 0.f};
#pragma unroll
    for (int rt = 0; rt < RT; rt++) {
#pragma unroll
        for (int tn = 0; tn < 4; tn++) {
            int gc = colBase + colOff + tn * 16 + ln;
            float bv = bias ? bias[gc] : 0.f;
#pragma unroll
            for (int r = 0; r < 4; r++) {
                long gr = rowBase + rowOff + rt * 16 + kg * 4 + r;
                if (gr < M) {
                    float v = acc[rt][tn][r] + bv;
                    if (relu) v = fmaxf(v, 0.f);
                    ushort_t sb = f2b(v);
                    C[gr * Nn + gc] = sb;
                    if (STATS) {
                        float vb = b2f(sb);
                        sums[tn] += vb;
                        sqs[tn] += vb * vb;
                    }
                }
            }
        }
    }
    if constexpr (STATS) {
#pragma unroll
        for (int tn = 0; tn < 4; tn++) {
            float s = sums[tn], q = sqs[tn];
            s += __shfl_xor(s, 16); q += __shfl_xor(q, 16);
            s += __shfl_xor(s, 32); q += __shfl_xor(q, 32);
            if (kg == 0) {
                int c = colOff + tn * 16 + ln;
                swred[wave * 2 * TN + c] = s;
                swred[wave * 2 * TN + TN + c] = q;
            }
        }
        __syncthreads();
        const int by = blockIdx.y;
        const int gyd = gridDim.y;
        for (int c = tid; c < TN; c += 256) {
            float ssum = 0.f, ssq = 0.f;
#pragma unroll
            for (int w = 0; w < 4; w++) {
                ssum += swred[w * 2 * TN + c];
                ssq  += swred[w * 2 * TN + TN + c];
            }
            long gc = colBase + c;
            partials[gc * gyd + by] = ssum;
            partials[((long)Nn + gc) * gyd + by] = ssq;
        }
    }
}

// ---------------- fused aggregate + MFMA GEMM (gx=1 layers) ----------------
template<int KP, int TN>
__global__ __launch_bounds__(256, 4) void k_gemm_agg(const ushort_t* __restrict__ y,
                                                  const int* __restrict__ cursor,
                                                  const int* __restrict__ elist,
                                                  const float* __restrict__ badd,
                                                  const ushort_t* __restrict__ BT,
                                                  const float* __restrict__ bias,
                                                  ushort_t* __restrict__ C,
                                                  float* __restrict__ partials,
                                                  int M, int Nn) {
    __shared__ __align__(16) ushort_t Af[128 * KP];
    __shared__ __align__(16) ushort_t Bs[TN * 32];
    float* swred = (float*)Af;           // alias: Af dead after K-loop (barrier below)
    const int tid = threadIdx.x;
    const int wave = tid >> 6, lane = tid & 63;
    const int ln = lane & 15, kg = lane >> 4;
    const long rowBase = (long)blockIdx.y * 128;
    constexpr int CPR = KP / 8;          // 16B chunks per row
    constexpr int TPR = CPR;
    constexpr int RPS = 256 / TPR;

    // ---- phase 1: aggregate into Af (chunk-XOR swizzle keyed on row) ----
    {
        const int lr = tid / TPR;
        const int ck = tid % TPR;
        const int c0 = ck * 8;
        float bd[8];
#pragma unroll
        for (int j = 0; j < 8; j++) bd[j] = badd[c0 + j];
        for (int s = 0; s < 128; s += RPS) {
            int r = s + lr;
            long gr = rowBase + r; if (gr >= M) gr = M - 1;
            int cnt = cursor[gr]; if (cnt > DEG_CAP) cnt = DEG_CAP;
            const int* el = elist + gr * DEG_CAP;
            int4 e0 = *(const int4*)el;
            int4 e1 = *(const int4*)(el + 4);
            int ids[8] = {e0.x, e0.y, e0.z, e0.w, e1.x, e1.y, e1.z, e1.w};
            ushort8v sv = *(const ushort8v*)(y + gr * KP + c0);
            ushort8v rr[8];
#pragma unroll
            for (int i = 0; i < 8; i++)
                if (i < cnt) rr[i] = *(const ushort8v*)(y + (long)ids[i] * KP + c0);
            float av[8];
#pragma unroll
            for (int j = 0; j < 8; j++) av[j] = b2f(sv[j]);
#pragma unroll
            for (int i = 0; i < 8; i++)
                if (i < cnt) {
#pragma unroll
                    for (int j = 0; j < 8; j++) av[j] += b2f(rr[i][j]);
                }
            for (int i = 8; i < cnt; i++) {
                ushort8v u = *(const ushort8v*)(y + (long)el[i] * KP + c0);
#pragma unroll
                for (int j = 0; j < 8; j++) av[j] += b2f(u[j]);
            }
            ushort8v ov;
#pragma unroll
            for (int j = 0; j < 8; j++) ov[j] = f2b(fmaxf(av[j] + bd[j], 0.f));
            int cks = ck ^ (r & (CPR - 1));
            *(ushort8v*)&Af[r * KP + cks * 8] = ov;
        }
    }

    // ---- phase 2: GEMM, A from LDS, B staged ----
    constexpr int RT = (TN == 128) ? 4 : 2;
    const int rowOff = (TN == 128) ? ((wave >> 1) * 64) : (wave * 32);
    const int colOff = (TN == 128) ? ((wave & 1) * 64) : 0;
    const ushort_t* bSrc[TN / 64];
#pragma unroll
    for (int i = 0; i < TN / 64; i++) {
        long cc = i * 64 + (tid >> 2);
        bSrc[i] = BT + cc * KP + (tid & 3) * 8;
    }
    ushort_t* bDst = Bs + wave * 512;

    floatx4 acc[RT][4];
#pragma unroll
    for (int i = 0; i < RT; i++)
#pragma unroll
        for (int j = 0; j < 4; j++) acc[i][j] = (floatx4){0.f, 0.f, 0.f, 0.f};

    for (int k0 = 0; k0 < KP; k0 += 32) {
        __syncthreads();
#pragma unroll
        for (int i = 0; i < TN / 64; i++)
            __builtin_amdgcn_global_load_lds(
                (const __attribute__((address_space(1))) void*)(bSrc[i] + k0),
                (__attribute__((address_space(3))) void*)(bDst + i * 2048), 16, 0, 0);
        __syncthreads();

        short8 afr[RT], bfr[4];
#pragma unroll
        for (int rt = 0; rt < RT; rt++) {
            int row = rowOff + rt * 16 + ln;
            int cks = ((k0 >> 3) + kg) ^ (row & (CPR - 1));
            afr[rt] = *(const short8*)&Af[row * KP + cks * 8];
        }
#pragma unroll
        for (int tn = 0; tn < 4; tn++)
            bfr[tn] = *(const short8*)&Bs[(colOff + tn * 16 + ln) * 32 + kg * 8];
#pragma unroll
        for (int rt = 0; rt < RT; rt++)
#pragma unroll
            for (int tn = 0; tn < 4; tn++)
                acc[rt][tn] = __builtin_amdgcn_mfma_f32_16x16x32_bf16(afr[rt], bfr[tn], acc[rt][tn], 0, 0, 0);
    }

    __syncthreads();
    for (int i = tid; i < 4 * 2 * TN; i += 256) swred[i] = 0.f;
    __syncthreads();

    float sums[4] = {0.f, 0.f, 0.f, 0.f};
    float sqs[4]  = {0.f, 0.f, 0.f, 0.f};
#pragma unroll
    for (int rt = 0; rt < RT; rt++) {
#pragma unroll
        for (int tn = 0; tn < 4; tn++) {
            int gc = colOff + tn * 16 + ln;
            float bv = bias[gc];
#pragma unroll
            for (int r = 0; r < 4; r++) {
                long gr = rowBase + rowOff + rt * 16 + kg * 4 + r;
                if (gr < M) {
                    float v = fmaxf(acc[rt][tn][r] + bv, 0.f);
                    ushort_t sb = f2b(v);
                    C[gr * Nn + gc] = sb;
                    float vb = b2f(sb);
                    sums[tn] += vb;
                    sqs[tn] += vb * vb;
                }
            }
        }
    }
#pragma unroll
    for (int tn = 0; tn < 4; tn++) {
        float s = sums[tn], q = sqs[tn];
        s += __shfl_xor(s, 16); q += __shfl_xor(q, 16);
        s += __shfl_xor(s, 32); q += __shfl_xor(q, 32);
        if (kg == 0) {
            int c = colOff + tn * 16 + ln;
            swred[wave * 2 * TN + c] = s;
            swred[wave * 2 * TN + TN + c] = q;
        }
    }
    __syncthreads();
    const int by = blockIdx.y;
    const int gyd = gridDim.y;
    for (int c = tid; c < TN; c += 256) {
        float ssum = 0.f, ssq = 0.f;
#pragma unroll
        for (int w = 0; w < 4; w++) {
            ssum += swred[w * 2 * TN + c];
            ssq  += swred[w * 2 * TN + TN + c];
        }
        partials[(long)c * gyd + by] = ssum;
        partials[((long)Nn + c) * gyd + by] = ssq;
    }
}

// ---------- standalone aggregate (layer 1, D=256), 256 threads = 4 nodes/block ----------
template<int D>
__global__ void k_aggregate(const ushort_t* __restrict__ y, const int* __restrict__ cursor,
                            const int* __restrict__ elist, const float* __restrict__ badd,
                            ushort_t* __restrict__ out, int nblk,
                            const float* __restrict__ Wn, ushort_t* __restrict__ BTn,
                            int KWn, int NWn) {
    int t = threadIdx.x;     // 256
    if ((int)blockIdx.x >= nblk) {
        int b = blockIdx.x - nblk;       // 0..NWn-1, one output row per block
        BTn[(long)b * KWn + t] = f2b(Wn[(long)t * NWn + b]);
        return;
    }
    const int CG = D / 4;                // 64 threads per node
    const int NPB = 256 / CG;            // 4 nodes per block
    int n = blockIdx.x * NPB + t / CG;
    int c = (t % CG) * 4;
    if (n >= N_NODES) return;
    int cnt = cursor[n];
    if (cnt > DEG_CAP) cnt = DEG_CAP;
    const int* el = elist + (long)n * DEG_CAP;
    int4 e0 = *(const int4*)el;
    int4 e1 = *(const int4*)(el + 4);
    int ids[8] = {e0.x, e0.y, e0.z, e0.w, e1.x, e1.y, e1.z, e1.w};
    ushort4v sv = *(const ushort4v*)(y + (long)n * D + c);
    ushort4v rr[8];
#pragma unroll
    for (int i = 0; i < 8; i++)
        if (i < cnt) rr[i] = *(const ushort4v*)(y + (long)ids[i] * D + c);
    float t0 = b2f(sv.x), t1 = b2f(sv.y), t2 = b2f(sv.z), t3 = b2f(sv.w);
#pragma unroll
    for (int i = 0; i < 8; i++)
        if (i < cnt) {
            t0 += b2f(rr[i].x); t1 += b2f(rr[i].y); t2 += b2f(rr[i].z); t3 += b2f(rr[i].w);
        }
    for (int i = 8; i < cnt; i++) {
        ushort4v u = *(const ushort4v*)(y + (long)el[i] * D + c);
        t0 += b2f(u.x); t1 += b2f(u.y); t2 += b2f(u.z); t3 += b2f(u.w);
    }
    t0 = fmaxf(t0 + badd[c + 0], 0.f);
    t1 = fmaxf(t1 + badd[c + 1], 0.f);
    t2 = fmaxf(t2 + badd[c + 2], 0.f);
    t3 = fmaxf(t3 + badd[c + 3], 0.f);
    ushort4v o = {f2b(t0), f2b(t1), f2b(t2), f2b(t3)};
    *(ushort4v*)(out + (long)n * D + c) = o;
}

// ---------- BN: reduce partials + finalize scsh; optional next-W prep ----------
__global__ void k_bn(const float* __restrict__ partials, int gy,
                     const float* __restrict__ gamma, const float* __restrict__ beta,
                     float* __restrict__ scsh, int K,
                     const float* __restrict__ Wn, ushort_t* __restrict__ BTn,
                     int KWn, int NWn) {
    int b = blockIdx.x;
    int t = threadIdx.x;   // 64
    if (b >= K) {
        int p = b - K;
        int nk = KWn >> 6;
        int n = p / nk, kc = p - n * nk;
        int k = kc * 64 + t;
        BTn[(long)n * KWn + k] = f2b(Wn[(long)k * NWn + n]);
        return;
    }
    const float* ps = partials + (long)b * gy;
    const float* pq = partials + (long)(K + b) * gy;
    float s = 0.f, q = 0.f;
    for (int i = t; i < gy; i += 64) { s += ps[i]; q += pq[i]; }
#pragma unroll
    for (int off = 32; off >= 1; off >>= 1) { s += __shfl_xor(s, off); q += __shfl_xor(q, off); }
    if (t == 0) {
        float invN = 1.0f / (float)N_NODES;
        float mu = s * invN;
        float var = fmaxf(q * invN - mu * mu, 0.f);
        float sc = rsqrtf(var + BN_EPS) * gamma[b];
        scsh[b] = sc;
        scsh[K + b] = beta[b] - mu * sc;
    }
}

// ---------- pool (segmented, BN affine fused) + head, fused ----------
__global__ void k_poolhead(const ushort_t* __restrict__ h, const int* __restrict__ batch,
                           const float* __restrict__ scsh,
                           const float* __restrict__ Wf1, const float* __restrict__ bf1,
                           const float* __restrict__ Wf2, const float* __restrict__ bf2,
                           float* __restrict__ out) {
    __shared__ float pl[64];
    __shared__ float hid[16];
    int g = blockIdx.x;
    int c = threadIdx.x;
    int lo = 0, hi = N_NODES;
    while (lo < hi) { int mid = (lo + hi) >> 1; if (batch[mid] < g) lo = mid + 1; else hi = mid; }
    int start = lo;
    hi = N_NODES;
    while (lo < hi) { int mid = (lo + hi) >> 1; if (batch[mid] < g + 1) lo = mid + 1; else hi = mid; }
    int end = lo;
    float s = 0.f;
    for (int r = start; r < end; r++) s += b2f(h[(long)r * 64 + c]);
    pl[c] = s * scsh[c] + scsh[64 + c] * (float)(end - start);
    __syncthreads();
    if (c < 16) {
        float sh = bf1[c];
        for (int j = 0; j < 64; j++) sh += pl[j] * Wf1[j * 16 + c];
        hid[c] = fmaxf(sh, 0.f);
    }
    __syncthreads();
    if (c == 0) {
        float o = bf2[0];
#pragma unroll
        for (int k = 0; k < 16; k++) o += hid[k] * Wf2[k];
        out[g] = fmaxf(o, 0.f);
    }
}

// ---------------- launch ----------------
extern "C" void kernel_launch(void* const* d_in, const int* in_sizes, int n_in,
                              void* d_out, int out_size, void* d_ws, size_t ws_size,
                              hipStream_t stream) {
    const float* x    = (const float*)d_in[0];
    const int*  ei    = (const int*)d_in[1];
    const int*  batch = (const int*)d_in[2];
    const float* W1a = (const float*)d_in[3];
    const float* b1a = (const float*)d_in[4];
    const float* W1b = (const float*)d_in[5];
    const float* b1b = (const float*)d_in[6];
    const float* g1  = (const float*)d_in[7];
    const float* be1 = (const float*)d_in[8];
    const float* W2a = (const float*)d_in[9];
    const float* b2a = (const float*)d_in[10];
    const float* W2b = (const float*)d_in[11];
    const float* b2b = (const float*)d_in[12];
    const float* g2  = (const float*)d_in[13];
    const float* be2 = (const float*)d_in[14];
    const float* W3a = (const float*)d_in[15];
    const float* b3a = (const float*)d_in[16];
    const float* W3b = (const float*)d_in[17];
    const float* b3b = (const float*)d_in[18];
    const float* g3  = (const float*)d_in[19];
    const float* be3 = (const float*)d_in[20];
    const float* Wf1 = (const float*)d_in[21];
    const float* bf1 = (const float*)d_in[22];
    const float* Wf2 = (const float*)d_in[23];
    const float* bf2 = (const float*)d_in[24];

    const int N = N_NODES, E = N_EDGES;
    const int* src = ei;
    const int* dst = ei + E;
    const int gy = (N + 127) / 128;   // 782 row-tiles

    // ---- workspace carve (256B aligned) ----
    char* wp = (char*)d_ws;
    auto carve = [&](size_t bytes) {
        char* p = wp;
        wp += (bytes + 255) & ~(size_t)255;
        return (void*)p;
    };
    ushort_t* xb     = (ushort_t*)carve((size_t)N * 384 * 2);
    ushort_t* bufA   = (ushort_t*)carve((size_t)N * 256 * 2);
    ushort_t* bufB   = (ushort_t*)carve((size_t)N * 256 * 2);
    int*      elist  = (int*)carve((size_t)N * DEG_CAP * 4);
    int*      cursor = (int*)carve((size_t)N * 4);
    ushort_t* BT1    = (ushort_t*)carve((size_t)256 * 384 * 2);
    ushort_t* BT2    = (ushort_t*)carve((size_t)256 * 384 * 2);
    float*    scsh   = (float*)carve(512 * 4);
    float*    biasE  = (float*)carve(256 * 4);
    float*    partials = (float*)carve((size_t)2 * 256 * gy * 4);  // 1.6 MB max

    dim3 blk(256);

    // ---- prep: pad x (+W1a prep, cursor zero), build in-edge buckets ----
    k_pad_x<<<N + 768, 128, 0, stream>>>(x, xb, cursor, W1a, BT1);
    k_fill<<<(E + 255) / 256, blk, 0, stream>>>(src, dst, cursor, elist);

    // ---------- layer 1: 373 -> 256 -> 256 ----------
    k_gemm<384, 128, false><<<dim3(2, gy), blk, 0, stream>>>(xb, BT1, nullptr, bufA, nullptr, N, 256, 0);
    k_aggregate<256><<<25000 + 256, blk, 0, stream>>>(bufA, cursor, elist, b1a, bufB, 25000, W1b, BT2, 256, 256);
    k_gemm<256, 128, true><<<dim3(2, gy), blk, 0, stream>>>(bufB, BT2, b1b, bufA, partials, N, 256, 1);
    k_bn<<<256 + 256, 64, 0, stream>>>(partials, gy, g1, be1, scsh, 256, W2b, BT2, 128, 128);

    // ---------- layer 2: 256 -> 128 -> 128 (BN folded into W2a + biasEff) ----------
    k_prep_scaled<<<dim3(2, 128), 128, 0, stream>>>(W2a, scsh, BT1, biasE, 256, 256, 128);
    k_gemm<256, 128, false><<<dim3(1, gy), blk, 0, stream>>>(bufA, BT1, biasE, bufB, nullptr, N, 128, 0);
    k_gemm_agg<128, 128><<<dim3(1, gy), blk, 0, stream>>>(bufB, cursor, elist, b2a, BT2, b2b, bufA, partials, N, 128);
    k_bn<<<128 + 64, 64, 0, stream>>>(partials, gy, g2, be2, scsh, 128, W3b, BT2, 64, 64);

    // ---------- layer 3: 128 -> 64 -> 64 ----------
    k_prep_scaled<<<dim3(1, 64), 128, 0, stream>>>(W3a, scsh, BT1, biasE, 128, 128, 64);
    k_gemm<128, 64, false><<<dim3(1, gy), blk, 0, stream>>>(bufA, BT1, biasE, bufB, nullptr, N, 64, 0);
    k_gemm_agg<64, 64><<<dim3(1, gy), blk, 0, stream>>>(bufB, cursor, elist, b3a, BT2, b3b, bufA, partials, N, 64);
    k_bn<<<64, 64, 0, stream>>>(partials, gy, g3, be3, scsh, 64, nullptr, nullptr, 64, 64);

    // ---------- pool + head (fused) ----------
    k_poolhead<<<N_GRAPHS, 64, 0, stream>>>(bufA, batch, scsh, Wf1, bf1, Wf2, bf2, (float*)d_out);
}